// Round 3
// baseline (209.229 us; speedup 1.0000x reference)
//
#include <hip/hip_runtime.h>

#define NB      1024
#define NWORLD  2048
#define DDIM    64
#define NWMAT   512
#define LISTCAP 32

typedef __attribute__((ext_vector_type(4))) float f32x4;
typedef __attribute__((ext_vector_type(8))) short bf16x8;

__device__ __forceinline__ unsigned short f2bf(float f) {
    union { float f; unsigned u; } v; v.f = f;
    unsigned u = v.u;
    u += 0x7fffu + ((u >> 16) & 1u);   // RNE round to bf16
    return (unsigned short)(u >> 16);
}

// ---- kernel 1: convert W and worlds to bf16 into workspace ----
__global__ __launch_bounds__(256)
void convert_bf16(const float* __restrict__ W, const float* __restrict__ worlds,
                  unsigned short* __restrict__ Wbf, unsigned short* __restrict__ worldsbf)
{
    const int NWE = NWMAT * DDIM * DDIM;   // 2097152
    const int NWO = NWORLD * DDIM;         // 131072
    int i = (blockIdx.x * 256 + threadIdx.x) * 8;
    if (i >= NWE + NWO) return;
    const float* src; unsigned short* dst; int off;
    if (i < NWE) { src = W;      dst = Wbf;      off = i; }
    else         { src = worlds; dst = worldsbf; off = i - NWE; }
    f32x4 a = *reinterpret_cast<const f32x4*>(src + off);
    f32x4 b = *reinterpret_cast<const f32x4*>(src + off + 4);
    bf16x8 r;
    r[0] = (short)f2bf(a[0]); r[1] = (short)f2bf(a[1]);
    r[2] = (short)f2bf(a[2]); r[3] = (short)f2bf(a[3]);
    r[4] = (short)f2bf(b[0]); r[5] = (short)f2bf(b[1]);
    r[6] = (short)f2bf(b[2]); r[7] = (short)f2bf(b[3]);
    *reinterpret_cast<bf16x8*>(dst + off) = r;
}

// ---- kernel 2: per-row match lists (stores W-index b), index-ordered ----
__global__ __launch_bounds__(64)
void build_lists(const int* __restrict__ nullary, int* __restrict__ cntw,
                 int* __restrict__ blist)
{
    const int r = blockIdx.x;
    const int lane = threadIdx.x;
    int base = 0;
    for (int c = 0; c < NB / 64; ++c) {
        const int n = c * 64 + lane;
        const bool m = (nullary[2 * n] == r);
        const unsigned long long mask = __ballot(m);
        if (m) {
            const int pos = base + __popcll(mask & ((1ull << lane) - 1ull));
            if (pos < LISTCAP) blist[r * LISTCAP + pos] = nullary[2 * n + 1];
        }
        base += __popcll(mask);
    }
    if (lane == 0) cntw[r] = (base > LISTCAP ? LISTCAP : base);
}

// ---- kernel 3: block-per-row fused gather-GEMM + L2norm + streaming write ----
__global__ __launch_bounds__(256)
void nullary_main(const unsigned short* __restrict__ Wbf,
                  const unsigned short* __restrict__ worldsbf,
                  const int* __restrict__ cntw,
                  const int* __restrict__ blist,
                  float* __restrict__ out)
{
    const int r   = blockIdx.x;      // 0..1023
    const int tid = threadIdx.x;
    float* orow = out + (size_t)r * DDIM * NWORLD;

    const int cnt = cntw[r];
    if (cnt == 0) {
        // pure linear 512 KB zero sweep (fill-kernel pattern), nontemporal
        const f32x4 z = {0.f, 0.f, 0.f, 0.f};
        f32x4* o = reinterpret_cast<f32x4*>(orow);
        #pragma unroll 8
        for (int i = tid; i < DDIM * NWORLD / 4; i += 256)
            __builtin_nontemporal_store(z, o + i);
        return;
    }

    const int wave = tid >> 6, lane = tid & 63;
    const int col  = lane & 15, krow = lane >> 4;
    const int drow = tid >> 5;        // 0..7   (store phase)
    const int wl   = (tid & 31) * 4;  // 0..124 (store phase)

    __shared__ float T[DDIM][132];
    __shared__ int s_b[LISTCAP];
    if (tid < cnt) s_b[tid] = blist[r * LISTCAP + tid];
    __syncthreads();

    for (int wt = 0; wt < 16; ++wt) {
        const int w0 = wt * 128 + wave * 32;

        // B fragments for this world tile
        bf16x8 bfrag[2][2];
        #pragma unroll
        for (int sub = 0; sub < 2; ++sub) {
            const unsigned short* wp = worldsbf + (size_t)(w0 + sub * 16 + col) * DDIM + krow * 8;
            bfrag[sub][0] = *reinterpret_cast<const bf16x8*>(wp);
            bfrag[sub][1] = *reinterpret_cast<const bf16x8*>(wp + 32);
        }

        f32x4 acc[2][4];
        #pragma unroll
        for (int s = 0; s < 2; ++s)
            #pragma unroll
            for (int m = 0; m < 4; ++m)
                acc[s][m] = (f32x4){0.f, 0.f, 0.f, 0.f};

        for (int mi = 0; mi < cnt; ++mi) {
            const unsigned short* Wb = Wbf + (size_t)s_b[mi] * DDIM * DDIM;
            bf16x8 afrag[4][2];
            #pragma unroll
            for (int mt = 0; mt < 4; ++mt) {
                const unsigned short* ap = Wb + (size_t)(mt * 16 + col) * DDIM + krow * 8;
                afrag[mt][0] = *reinterpret_cast<const bf16x8*>(ap);
                afrag[mt][1] = *reinterpret_cast<const bf16x8*>(ap + 32);
            }
            #pragma unroll
            for (int sub = 0; sub < 2; ++sub) {
                f32x4 x[4];
                #pragma unroll
                for (int mt = 0; mt < 4; ++mt) {
                    f32x4 c = {0.f, 0.f, 0.f, 0.f};
                    c = __builtin_amdgcn_mfma_f32_16x16x32_bf16(afrag[mt][0], bfrag[sub][0], c, 0, 0, 0);
                    c = __builtin_amdgcn_mfma_f32_16x16x32_bf16(afrag[mt][1], bfrag[sub][1], c, 0, 0, 0);
                    x[mt] = c;
                }
                float p = 0.f;
                #pragma unroll
                for (int mt = 0; mt < 4; ++mt)
                    #pragma unroll
                    for (int j = 0; j < 4; ++j)
                        p += x[mt][j] * x[mt][j];
                p += __shfl_xor(p, 16, 64);
                p += __shfl_xor(p, 32, 64);
                const float s = rsqrtf(fmaxf(p, 1e-12f));
                #pragma unroll
                for (int mt = 0; mt < 4; ++mt)
                    #pragma unroll
                    for (int j = 0; j < 4; ++j)
                        acc[sub][mt][j] += x[mt][j] * s;
            }
        }

        if (wt) __syncthreads();   // WAR: prior tile's T reads done
        #pragma unroll
        for (int sub = 0; sub < 2; ++sub)
            #pragma unroll
            for (int mt = 0; mt < 4; ++mt)
                #pragma unroll
                for (int j = 0; j < 4; ++j)
                    T[mt * 16 + krow * 4 + j][wave * 32 + sub * 16 + col] = acc[sub][mt][j];
        __syncthreads();

        float* obase = orow + wt * 128;
        #pragma unroll
        for (int rd = 0; rd < 8; ++rd) {
            const int d = rd * 8 + drow;
            const f32x4 v = *reinterpret_cast<const f32x4*>(&T[d][wl]);
            __builtin_nontemporal_store(v, reinterpret_cast<f32x4*>(obase + (size_t)d * NWORLD + wl));
        }
    }
}

extern "C" void kernel_launch(void* const* d_in, const int* in_sizes, int n_in,
                              void* d_out, int out_size, void* d_ws, size_t ws_size,
                              hipStream_t stream) {
    const float* worlds  = (const float*)d_in[0];
    const float* W       = (const float*)d_in[1];
    const int*   nullary = (const int*)d_in[2];
    float*       out     = (float*)d_out;

    unsigned short* Wbf      = (unsigned short*)d_ws;
    unsigned short* worldsbf = Wbf + (size_t)NWMAT * DDIM * DDIM;        // +4 MB
    int*            cntw     = (int*)(worldsbf + (size_t)NWORLD * DDIM); // +256 KB
    int*            blist    = cntw + NB;

    convert_bf16<<<(NWMAT * DDIM * DDIM + NWORLD * DDIM) / (256 * 8), 256, 0, stream>>>(
        W, worlds, Wbf, worldsbf);
    build_lists<<<NB, 64, 0, stream>>>(nullary, cntw, blist);
    nullary_main<<<NB, 256, 0, stream>>>(Wbf, worldsbf, cntw, blist, out);
}

// Round 4
// 183.985 us; speedup vs baseline: 1.1372x; 1.1372x over previous
//
#include <hip/hip_runtime.h>

#define NB      1024
#define NWORLD  2048
#define DDIM    64
#define NWMAT   512
#define LISTCAP 32
#define CONV_BLOCKS 1088   // (NWMAT*64*64 + NWORLD*64) / (256*8) = 1088 exactly

typedef __attribute__((ext_vector_type(4))) float f32x4;
typedef __attribute__((ext_vector_type(8))) short bf16x8;

__device__ __forceinline__ unsigned short f2bf(float f) {
    union { float f; unsigned u; } v; v.f = f;
    unsigned u = v.u;
    u += 0x7fffu + ((u >> 16) & 1u);   // RNE round to bf16
    return (unsigned short)(u >> 16);
}

// ---- kernel 1: fused {f32->bf16 convert} + {per-row match lists + row compaction} ----
__global__ __launch_bounds__(256)
void prep(const float* __restrict__ W, const float* __restrict__ worlds,
          const int* __restrict__ nullary,
          unsigned short* __restrict__ Wbf, unsigned short* __restrict__ worldsbf,
          int* __restrict__ cntw, int* __restrict__ blist,
          int* __restrict__ counters /* [0]=zcnt [1]=mcnt */,
          int* __restrict__ zlist, int* __restrict__ mlist)
{
    const int bid = blockIdx.x;
    if (bid < CONV_BLOCKS) {
        const int NWE = NWMAT * DDIM * DDIM;   // 2097152
        int i = (bid * 256 + threadIdx.x) * 8;
        const float* src; unsigned short* dst; int off;
        if (i < NWE) { src = W;      dst = Wbf;      off = i; }
        else         { src = worlds; dst = worldsbf; off = i - NWE; }
        f32x4 a = *reinterpret_cast<const f32x4*>(src + off);
        f32x4 b = *reinterpret_cast<const f32x4*>(src + off + 4);
        bf16x8 r;
        r[0] = (short)f2bf(a[0]); r[1] = (short)f2bf(a[1]);
        r[2] = (short)f2bf(a[2]); r[3] = (short)f2bf(a[3]);
        r[4] = (short)f2bf(b[0]); r[5] = (short)f2bf(b[1]);
        r[6] = (short)f2bf(b[2]); r[7] = (short)f2bf(b[3]);
        *reinterpret_cast<bf16x8*>(dst + off) = r;
        return;
    }
    // list blocks: 256 blocks x 4 rows (one row per wave)
    const int r    = (bid - CONV_BLOCKS) * 4 + (threadIdx.x >> 6);
    const int lane = threadIdx.x & 63;
    int base = 0;
    for (int c = 0; c < NB / 64; ++c) {
        const int n = c * 64 + lane;
        const bool m = (nullary[2 * n] == r);
        const unsigned long long mask = __ballot(m);
        if (m) {
            const int pos = base + __popcll(mask & ((1ull << lane) - 1ull));
            if (pos < LISTCAP) blist[r * LISTCAP + pos] = nullary[2 * n + 1];
        }
        base += __popcll(mask);
    }
    if (lane == 0) {
        const int cnt = (base > LISTCAP ? LISTCAP : base);
        cntw[r] = cnt;
        if (cnt == 0) { int p = atomicAdd(&counters[0], 1); zlist[p] = r; }
        else          { int p = atomicAdd(&counters[1], 1); mlist[p] = r; }
    }
}

// ---- kernel 2: matched rows only. grid (8, 1024); block = 2 world-tiles x 1 row ----
__global__ __launch_bounds__(256)
void matched(const unsigned short* __restrict__ Wbf,
             const unsigned short* __restrict__ worldsbf,
             const int* __restrict__ cntw, const int* __restrict__ blist,
             const int* __restrict__ counters, const int* __restrict__ mlist,
             float* __restrict__ out)
{
    if ((int)blockIdx.y >= counters[1]) return;
    const int r   = mlist[blockIdx.y];
    const int cnt = cntw[r];
    const int tid = threadIdx.x;

    const int wave = tid >> 6, lane = tid & 63;
    const int col  = lane & 15, krow = lane >> 4;
    const int drow = tid >> 5;        // 0..7   (store phase)
    const int wl   = (tid & 31) * 4;  // 0..124 (store phase)

    __shared__ float T[DDIM][132];
    __shared__ int s_b[LISTCAP];
    if (tid < cnt) s_b[tid] = blist[r * LISTCAP + tid];
    __syncthreads();

    float* orow = out + (size_t)r * DDIM * NWORLD;

    #pragma unroll
    for (int half = 0; half < 2; ++half) {
        const int wt = blockIdx.x * 2 + half;
        const int w0 = wt * 128 + wave * 32;

        bf16x8 bfrag[2][2];
        #pragma unroll
        for (int sub = 0; sub < 2; ++sub) {
            const unsigned short* wp = worldsbf + (size_t)(w0 + sub * 16 + col) * DDIM + krow * 8;
            bfrag[sub][0] = *reinterpret_cast<const bf16x8*>(wp);
            bfrag[sub][1] = *reinterpret_cast<const bf16x8*>(wp + 32);
        }

        f32x4 acc[2][4];
        #pragma unroll
        for (int s = 0; s < 2; ++s)
            #pragma unroll
            for (int m = 0; m < 4; ++m)
                acc[s][m] = (f32x4){0.f, 0.f, 0.f, 0.f};

        for (int mi = 0; mi < cnt; ++mi) {
            const unsigned short* Wb = Wbf + (size_t)s_b[mi] * DDIM * DDIM;
            bf16x8 afrag[4][2];
            #pragma unroll
            for (int mt = 0; mt < 4; ++mt) {
                const unsigned short* ap = Wb + (size_t)(mt * 16 + col) * DDIM + krow * 8;
                afrag[mt][0] = *reinterpret_cast<const bf16x8*>(ap);
                afrag[mt][1] = *reinterpret_cast<const bf16x8*>(ap + 32);
            }
            #pragma unroll
            for (int sub = 0; sub < 2; ++sub) {
                f32x4 x[4];
                #pragma unroll
                for (int mt = 0; mt < 4; ++mt) {
                    f32x4 c = {0.f, 0.f, 0.f, 0.f};
                    c = __builtin_amdgcn_mfma_f32_16x16x32_bf16(afrag[mt][0], bfrag[sub][0], c, 0, 0, 0);
                    c = __builtin_amdgcn_mfma_f32_16x16x32_bf16(afrag[mt][1], bfrag[sub][1], c, 0, 0, 0);
                    x[mt] = c;
                }
                float p = 0.f;
                #pragma unroll
                for (int mt = 0; mt < 4; ++mt)
                    #pragma unroll
                    for (int j = 0; j < 4; ++j)
                        p += x[mt][j] * x[mt][j];
                p += __shfl_xor(p, 16, 64);
                p += __shfl_xor(p, 32, 64);
                const float s = rsqrtf(fmaxf(p, 1e-12f));
                #pragma unroll
                for (int mt = 0; mt < 4; ++mt)
                    #pragma unroll
                    for (int j = 0; j < 4; ++j)
                        acc[sub][mt][j] += x[mt][j] * s;
            }
        }

        if (half) __syncthreads();   // WAR on T across halves
        #pragma unroll
        for (int sub = 0; sub < 2; ++sub)
            #pragma unroll
            for (int mt = 0; mt < 4; ++mt)
                #pragma unroll
                for (int j = 0; j < 4; ++j)
                    T[mt * 16 + krow * 4 + j][wave * 32 + sub * 16 + col] = acc[sub][mt][j];
        __syncthreads();

        float* obase = orow + wt * 128;
        #pragma unroll
        for (int rd = 0; rd < 8; ++rd) {
            const int d = rd * 8 + drow;
            const f32x4 v = *reinterpret_cast<const f32x4*>(&T[d][wl]);
            __builtin_nontemporal_store(v, reinterpret_cast<f32x4*>(obase + (size_t)d * NWORLD + wl));
        }
    }
}

// ---- kernel 3: zero-fill unmatched rows, fill-kernel store pattern ----
__global__ __launch_bounds__(256)
void zfill(const int* __restrict__ counters, const int* __restrict__ zlist,
           float* __restrict__ out)
{
    const int zc = counters[0];
    const int total = zc * 16;               // 32 KB chunks per row
    const f32x4 z = {0.f, 0.f, 0.f, 0.f};
    for (int chunk = blockIdx.x; chunk < total; chunk += gridDim.x) {
        const int r = zlist[chunk >> 4];
        f32x4* o = reinterpret_cast<f32x4*>(out + (size_t)r * DDIM * NWORLD
                                            + (size_t)(chunk & 15) * 8192) + threadIdx.x;
        #pragma unroll
        for (int j = 0; j < 8; ++j)
            __builtin_nontemporal_store(z, o + j * 256);
    }
}

extern "C" void kernel_launch(void* const* d_in, const int* in_sizes, int n_in,
                              void* d_out, int out_size, void* d_ws, size_t ws_size,
                              hipStream_t stream) {
    const float* worlds  = (const float*)d_in[0];
    const float* W       = (const float*)d_in[1];
    const int*   nullary = (const int*)d_in[2];
    float*       out     = (float*)d_out;

    unsigned short* Wbf      = (unsigned short*)d_ws;
    unsigned short* worldsbf = Wbf + (size_t)NWMAT * DDIM * DDIM;        // +4 MB
    int* cntw     = (int*)(worldsbf + (size_t)NWORLD * DDIM);            // +256 KB
    int* blist    = cntw + NB;
    int* counters = blist + NB * LISTCAP;
    int* zlist    = counters + 2;
    int* mlist    = zlist + NB;

    hipMemsetAsync(counters, 0, 2 * sizeof(int), stream);
    prep<<<CONV_BLOCKS + NB / 4, 256, 0, stream>>>(W, worlds, nullary, Wbf, worldsbf,
                                                   cntw, blist, counters, zlist, mlist);
    matched<<<dim3(8, NB), 256, 0, stream>>>(Wbf, worldsbf, cntw, blist, counters, mlist, out);
    zfill<<<2048, 256, 0, stream>>>(counters, zlist, out);
}

// Round 5
// 169.350 us; speedup vs baseline: 1.2355x; 1.0864x over previous
//
#include <hip/hip_runtime.h>

#define NB      1024
#define NWORLD  2048
#define DDIM    64
#define NWMAT   512
#define LISTCAP 32
#define CONV_BLOCKS 1088   // (NWMAT*64*64 + NWORLD*64) / (256*8) = 1088 exactly
#define MBLOCKS (NB * 8)   // matched capacity: 8 blocks/row (2 tiles each)
#define ZBLOCKS 2048       // fill blocks (grid-stride)

typedef __attribute__((ext_vector_type(4))) float f32x4;
typedef __attribute__((ext_vector_type(8))) short bf16x8;

__device__ __forceinline__ unsigned short f2bf(float f) {
    union { float f; unsigned u; } v; v.f = f;
    unsigned u = v.u;
    u += 0x7fffu + ((u >> 16) & 1u);   // RNE round to bf16
    return (unsigned short)(u >> 16);
}

// ---- kernel 1: fused {f32->bf16 convert} + {per-row match lists + row compaction} ----
__global__ __launch_bounds__(256)
void prep(const float* __restrict__ W, const float* __restrict__ worlds,
          const int* __restrict__ nullary,
          unsigned short* __restrict__ Wbf, unsigned short* __restrict__ worldsbf,
          int* __restrict__ blist,
          int* __restrict__ counters /* [0]=zcnt [1]=mcnt */,
          int* __restrict__ zlist, int* __restrict__ mlist)
{
    const int bid = blockIdx.x;
    if (bid < CONV_BLOCKS) {
        const int NWE = NWMAT * DDIM * DDIM;   // 2097152
        int i = (bid * 256 + threadIdx.x) * 8;
        const float* src; unsigned short* dst; int off;
        if (i < NWE) { src = W;      dst = Wbf;      off = i; }
        else         { src = worlds; dst = worldsbf; off = i - NWE; }
        f32x4 a = *reinterpret_cast<const f32x4*>(src + off);
        f32x4 b = *reinterpret_cast<const f32x4*>(src + off + 4);
        bf16x8 r;
        r[0] = (short)f2bf(a[0]); r[1] = (short)f2bf(a[1]);
        r[2] = (short)f2bf(a[2]); r[3] = (short)f2bf(a[3]);
        r[4] = (short)f2bf(b[0]); r[5] = (short)f2bf(b[1]);
        r[6] = (short)f2bf(b[2]); r[7] = (short)f2bf(b[3]);
        *reinterpret_cast<bf16x8*>(dst + off) = r;
        return;
    }
    // list blocks: 256 blocks x 4 rows (one row per wave)
    const int r    = (bid - CONV_BLOCKS) * 4 + (threadIdx.x >> 6);
    const int lane = threadIdx.x & 63;
    int base = 0;
    for (int c = 0; c < NB / 64; ++c) {
        const int n = c * 64 + lane;
        const bool m = (nullary[2 * n] == r);
        const unsigned long long mask = __ballot(m);
        if (m) {
            const int pos = base + __popcll(mask & ((1ull << lane) - 1ull));
            if (pos < LISTCAP) blist[r * LISTCAP + pos] = nullary[2 * n + 1];
        }
        base += __popcll(mask);
    }
    if (lane == 0) {
        const int cnt = (base > LISTCAP ? LISTCAP : base);
        if (cnt == 0) { int p = atomicAdd(&counters[0], 1); zlist[p] = r; }
        else          { int p = atomicAdd(&counters[1], 1); mlist[p] = r | (cnt << 16); }
    }
}

// ---- kernel 2: merged matched-GEMM + zero-fill (heterogeneous block roles) ----
// blocks [0, MBLOCKS): matched role, idx/8 -> mlist entry, 2 world-tiles each.
// blocks [MBLOCKS, MBLOCKS+ZBLOCKS): fill role, grid-stride over zero-row 32KB chunks.
__global__ __launch_bounds__(256)
void main2(const unsigned short* __restrict__ Wbf,
           const unsigned short* __restrict__ worldsbf,
           const int* __restrict__ blist,
           const int* __restrict__ counters,
           const int* __restrict__ zlist, const int* __restrict__ mlist,
           float* __restrict__ out)
{
    const int bid = blockIdx.x;
    const int tid = threadIdx.x;

    if (bid >= MBLOCKS) {
        // ---- fill role ----
        const int fid = bid - MBLOCKS;
        const int total = counters[0] * 16;      // 32KB chunks
        const f32x4 z = {0.f, 0.f, 0.f, 0.f};
        for (int chunk = fid; chunk < total; chunk += ZBLOCKS) {
            const int r = zlist[chunk >> 4];
            f32x4* o = reinterpret_cast<f32x4*>(out + (size_t)r * DDIM * NWORLD
                                                + (size_t)(chunk & 15) * 8192) + tid;
            #pragma unroll
            for (int j = 0; j < 8; ++j)
                o[j * 256] = z;
        }
        return;
    }

    // ---- matched role ----
    const int ridx = bid >> 3;
    if (ridx >= counters[1]) return;
    const int packed = mlist[ridx];
    const int r   = packed & 0xFFFF;
    const int cnt = packed >> 16;

    const int wave = tid >> 6, lane = tid & 63;
    const int col  = lane & 15, krow = lane >> 4;
    const int drow = tid >> 5;        // 0..7   (store phase)
    const int wl   = (tid & 31) * 4;  // 0..124 (store phase)

    __shared__ float T[DDIM][132];
    __shared__ int s_b[LISTCAP];
    if (tid < cnt) s_b[tid] = blist[r * LISTCAP + tid];
    __syncthreads();

    float* orow = out + (size_t)r * DDIM * NWORLD;

    #pragma unroll
    for (int half = 0; half < 2; ++half) {
        const int wt = (bid & 7) * 2 + half;
        const int w0 = wt * 128 + wave * 32;

        bf16x8 bfrag[2][2];
        #pragma unroll
        for (int sub = 0; sub < 2; ++sub) {
            const unsigned short* wp = worldsbf + (size_t)(w0 + sub * 16 + col) * DDIM + krow * 8;
            bfrag[sub][0] = *reinterpret_cast<const bf16x8*>(wp);
            bfrag[sub][1] = *reinterpret_cast<const bf16x8*>(wp + 32);
        }

        f32x4 acc[2][4];
        #pragma unroll
        for (int s = 0; s < 2; ++s)
            #pragma unroll
            for (int m = 0; m < 4; ++m)
                acc[s][m] = (f32x4){0.f, 0.f, 0.f, 0.f};

        for (int mi = 0; mi < cnt; ++mi) {
            const unsigned short* Wb = Wbf + (size_t)s_b[mi] * DDIM * DDIM;
            bf16x8 afrag[4][2];
            #pragma unroll
            for (int mt = 0; mt < 4; ++mt) {
                const unsigned short* ap = Wb + (size_t)(mt * 16 + col) * DDIM + krow * 8;
                afrag[mt][0] = *reinterpret_cast<const bf16x8*>(ap);
                afrag[mt][1] = *reinterpret_cast<const bf16x8*>(ap + 32);
            }
            #pragma unroll
            for (int sub = 0; sub < 2; ++sub) {
                f32x4 x[4];
                #pragma unroll
                for (int mt = 0; mt < 4; ++mt) {
                    f32x4 c = {0.f, 0.f, 0.f, 0.f};
                    c = __builtin_amdgcn_mfma_f32_16x16x32_bf16(afrag[mt][0], bfrag[sub][0], c, 0, 0, 0);
                    c = __builtin_amdgcn_mfma_f32_16x16x32_bf16(afrag[mt][1], bfrag[sub][1], c, 0, 0, 0);
                    x[mt] = c;
                }
                float p = 0.f;
                #pragma unroll
                for (int mt = 0; mt < 4; ++mt)
                    #pragma unroll
                    for (int j = 0; j < 4; ++j)
                        p += x[mt][j] * x[mt][j];
                p += __shfl_xor(p, 16, 64);
                p += __shfl_xor(p, 32, 64);
                const float s = rsqrtf(fmaxf(p, 1e-12f));
                #pragma unroll
                for (int mt = 0; mt < 4; ++mt)
                    #pragma unroll
                    for (int j = 0; j < 4; ++j)
                        acc[sub][mt][j] += x[mt][j] * s;
            }
        }

        if (half) __syncthreads();   // WAR on T across halves
        #pragma unroll
        for (int sub = 0; sub < 2; ++sub)
            #pragma unroll
            for (int mt = 0; mt < 4; ++mt)
                #pragma unroll
                for (int j = 0; j < 4; ++j)
                    T[mt * 16 + krow * 4 + j][wave * 32 + sub * 16 + col] = acc[sub][mt][j];
        __syncthreads();

        float* obase = orow + wt * 128;
        #pragma unroll
        for (int rd = 0; rd < 8; ++rd) {
            const int d = rd * 8 + drow;
            const f32x4 v = *reinterpret_cast<const f32x4*>(&T[d][wl]);
            *reinterpret_cast<f32x4*>(obase + (size_t)d * NWORLD + wl) = v;
        }
    }
}

extern "C" void kernel_launch(void* const* d_in, const int* in_sizes, int n_in,
                              void* d_out, int out_size, void* d_ws, size_t ws_size,
                              hipStream_t stream) {
    const float* worlds  = (const float*)d_in[0];
    const float* W       = (const float*)d_in[1];
    const int*   nullary = (const int*)d_in[2];
    float*       out     = (float*)d_out;

    unsigned short* Wbf      = (unsigned short*)d_ws;
    unsigned short* worldsbf = Wbf + (size_t)NWMAT * DDIM * DDIM;        // +4 MB
    int* blist    = (int*)(worldsbf + (size_t)NWORLD * DDIM);            // +256 KB
    int* counters = blist + NB * LISTCAP;
    int* zlist    = counters + 2;
    int* mlist    = zlist + NB;

    hipMemsetAsync(counters, 0, 2 * sizeof(int), stream);
    prep<<<CONV_BLOCKS + NB / 4, 256, 0, stream>>>(W, worlds, nullary, Wbf, worldsbf,
                                                   blist, counters, zlist, mlist);
    main2<<<MBLOCKS + ZBLOCKS, 256, 0, stream>>>(Wbf, worldsbf, blist, counters,
                                                 zlist, mlist, out);
}

// Round 6
// 128.690 us; speedup vs baseline: 1.6258x; 1.3160x over previous
//
#include <hip/hip_runtime.h>

#define NB      1024
#define NWORLD  2048
#define DDIM    64
#define NWMAT   512
#define LISTCAP 32
#define CONV_BLOCKS 1088      // (512*64*64 + 2048*64) / (256*8)
#define GRID_MAIN   6144      // 4096 matched slots + 2048 fill, interleaved bid%3
#define STASH_ROW   512
#define STASH_ROWS  9         // rows 512..520 hold the stash, zeroed by tail kernel

// stash byte offsets inside d_out (stash base = row 512 = byte 256 MiB)
#define STASH_BYTE  268435456ull
#define OFF_WBF     0ull            // 4 MiB  bf16 W
#define OFF_WORLDS  4194304ull      // 256 KiB bf16 worlds
#define OFF_MLIST   4456448ull      // 2 KiB   packed (cnt<<16|r)
#define OFF_BLIST   4458496ull      // 64 KiB  per-row W indices

typedef __attribute__((ext_vector_type(4))) float f32x4;
typedef __attribute__((ext_vector_type(8))) short bf16x8;

__device__ __forceinline__ unsigned short f2bf(float f) {
    union { float f; unsigned u; } v; v.f = f;
    unsigned u = v.u;
    u += 0x7fffu + ((u >> 16) & 1u);   // RNE round to bf16
    return (unsigned short)(u >> 16);
}

// ---- kernel 1: fused {f32->bf16 convert into stash} + {match lists into stash} ----
__global__ __launch_bounds__(256)
void prep(const float* __restrict__ W, const float* __restrict__ worlds,
          const int* __restrict__ nullary,
          char* outb, int* counters /* ws: [0]=zcnt [1]=mcnt */, int* zlist /* ws */)
{
    unsigned short* Wbf      = (unsigned short*)(outb + STASH_BYTE + OFF_WBF);
    unsigned short* worldsbf = (unsigned short*)(outb + STASH_BYTE + OFF_WORLDS);
    int* mlist               = (int*)(outb + STASH_BYTE + OFF_MLIST);
    int* blist               = (int*)(outb + STASH_BYTE + OFF_BLIST);

    const int bid = blockIdx.x;
    if (bid < CONV_BLOCKS) {
        const int NWE = NWMAT * DDIM * DDIM;   // 2097152
        int i = (bid * 256 + threadIdx.x) * 8;
        const float* src; unsigned short* dst; int off;
        if (i < NWE) { src = W;      dst = Wbf;      off = i; }
        else         { src = worlds; dst = worldsbf; off = i - NWE; }
        f32x4 a = *reinterpret_cast<const f32x4*>(src + off);
        f32x4 b = *reinterpret_cast<const f32x4*>(src + off + 4);
        bf16x8 r;
        r[0] = (short)f2bf(a[0]); r[1] = (short)f2bf(a[1]);
        r[2] = (short)f2bf(a[2]); r[3] = (short)f2bf(a[3]);
        r[4] = (short)f2bf(b[0]); r[5] = (short)f2bf(b[1]);
        r[6] = (short)f2bf(b[2]); r[7] = (short)f2bf(b[3]);
        *reinterpret_cast<bf16x8*>(dst + off) = r;
        return;
    }
    // list blocks: 256 blocks x 4 rows (one row per wave)
    const int r    = (bid - CONV_BLOCKS) * 4 + (threadIdx.x >> 6);
    const int lane = threadIdx.x & 63;
    int base = 0;
    for (int c = 0; c < NB / 64; ++c) {
        const int n = c * 64 + lane;
        const bool m = (nullary[2 * n] == r);
        const unsigned long long mask = __ballot(m);
        if (m && r < NWMAT) {
            const int pos = base + __popcll(mask & ((1ull << lane) - 1ull));
            if (pos < LISTCAP) blist[r * LISTCAP + pos] = nullary[2 * n + 1];
        }
        base += __popcll(mask);
    }
    if (lane == 0) {
        const int cnt = (base > LISTCAP ? LISTCAP : base);
        if (cnt == 0 || r >= NWMAT) {
            // stash rows are zeroed by the tail kernel, not the fill role
            if (r < STASH_ROW || r >= STASH_ROW + STASH_ROWS) {
                int p = atomicAdd(&counters[0], 1); zlist[p] = r;
            }
        } else {
            int p = atomicAdd(&counters[1], 1); mlist[p] = r | (cnt << 16);
        }
    }
}

// ---- kernel 2: merged matched-GEMM + zero-fill, roles interleaved in dispatch ----
// bid%3==2 -> fill role (2048 blocks, static chunk stride).
// else     -> matched slot mat=(bid/3)*2+(bid%3) in [0,4096): row mlist[mat>>3], tiles 2*(mat&7)+{0,1}.
__global__ __launch_bounds__(256)
void main2(char* outb, int* counters, const int* __restrict__ zlist)
{
    const unsigned short* Wbf      = (const unsigned short*)(outb + STASH_BYTE + OFF_WBF);
    const unsigned short* worldsbf = (const unsigned short*)(outb + STASH_BYTE + OFF_WORLDS);
    const int* mlist               = (const int*)(outb + STASH_BYTE + OFF_MLIST);
    const int* blist               = (const int*)(outb + STASH_BYTE + OFF_BLIST);
    float* out                     = (float*)outb;

    const int bid = blockIdx.x;
    const int tid = threadIdx.x;

    if (bid % 3 == 2) {
        // ---- fill role: static assignment, 32KB chunks over zero rows ----
        const int fid = bid / 3;                 // 0..2047
        const int total = counters[0] * 16;
        const f32x4 z = {0.f, 0.f, 0.f, 0.f};
        for (int chunk = fid; chunk < total; chunk += 2048) {
            const int r = zlist[chunk >> 4];
            f32x4* o = reinterpret_cast<f32x4*>(out + (size_t)r * DDIM * NWORLD
                                                + (size_t)(chunk & 15) * 8192) + tid;
            #pragma unroll
            for (int j = 0; j < 8; ++j)
                o[j * 256] = z;
        }
        return;
    }

    // ---- matched role ----
    const int mat  = (bid / 3) * 2 + (bid % 3);
    const int ridx = mat >> 3;
    if (ridx >= counters[1]) return;
    const int packed = mlist[ridx];
    const int r   = packed & 0xFFFF;
    const int cnt = packed >> 16;

    const int wave = tid >> 6, lane = tid & 63;
    const int col  = lane & 15, krow = lane >> 4;
    const int drow = tid >> 5;        // 0..7   (store phase)
    const int wl   = (tid & 31) * 4;  // 0..124 (store phase)

    __shared__ float T[DDIM][132];
    __shared__ int s_b[LISTCAP];
    if (tid < cnt) s_b[tid] = blist[r * LISTCAP + tid];
    __syncthreads();

    const int wtA = (mat & 7) * 2;    // tiles wtA, wtA+1

    // B fragments for BOTH tiles, hoisted (mi-invariant)
    bf16x8 bfrag[2][2][2];
    #pragma unroll
    for (int t = 0; t < 2; ++t)
        #pragma unroll
        for (int sub = 0; sub < 2; ++sub) {
            const int w0 = (wtA + t) * 128 + wave * 32 + sub * 16 + col;
            const unsigned short* wp = worldsbf + (size_t)w0 * DDIM + krow * 8;
            bfrag[t][sub][0] = *reinterpret_cast<const bf16x8*>(wp);
            bfrag[t][sub][1] = *reinterpret_cast<const bf16x8*>(wp + 32);
        }

    f32x4 acc[2][2][4];
    #pragma unroll
    for (int t = 0; t < 2; ++t)
        #pragma unroll
        for (int s = 0; s < 2; ++s)
            #pragma unroll
            for (int m = 0; m < 4; ++m)
                acc[t][s][m] = (f32x4){0.f, 0.f, 0.f, 0.f};

    // mi-outer: afrag loaded ONCE per match, reused across both tiles
    for (int mi = 0; mi < cnt; ++mi) {
        const unsigned short* Wb = Wbf + (size_t)s_b[mi] * DDIM * DDIM;
        bf16x8 afrag[4][2];
        #pragma unroll
        for (int mt = 0; mt < 4; ++mt) {
            const unsigned short* ap = Wb + (size_t)(mt * 16 + col) * DDIM + krow * 8;
            afrag[mt][0] = *reinterpret_cast<const bf16x8*>(ap);
            afrag[mt][1] = *reinterpret_cast<const bf16x8*>(ap + 32);
        }
        #pragma unroll
        for (int t = 0; t < 2; ++t)
            #pragma unroll
            for (int sub = 0; sub < 2; ++sub) {
                f32x4 x[4];
                #pragma unroll
                for (int mt = 0; mt < 4; ++mt) {
                    f32x4 c = {0.f, 0.f, 0.f, 0.f};
                    c = __builtin_amdgcn_mfma_f32_16x16x32_bf16(afrag[mt][0], bfrag[t][sub][0], c, 0, 0, 0);
                    c = __builtin_amdgcn_mfma_f32_16x16x32_bf16(afrag[mt][1], bfrag[t][sub][1], c, 0, 0, 0);
                    x[mt] = c;
                }
                float p = 0.f;
                #pragma unroll
                for (int mt = 0; mt < 4; ++mt)
                    #pragma unroll
                    for (int j = 0; j < 4; ++j)
                        p += x[mt][j] * x[mt][j];
                p += __shfl_xor(p, 16, 64);
                p += __shfl_xor(p, 32, 64);
                const float s = rsqrtf(fmaxf(p, 1e-12f));
                #pragma unroll
                for (int mt = 0; mt < 4; ++mt)
                    #pragma unroll
                    for (int j = 0; j < 4; ++j)
                        acc[t][sub][mt][j] += x[mt][j] * s;
            }
    }

    // store both tiles through LDS transpose
    float* orow = out + (size_t)r * DDIM * NWORLD;
    #pragma unroll
    for (int t = 0; t < 2; ++t) {
        if (t) __syncthreads();   // WAR: tile0 reads done before overwrite
        #pragma unroll
        for (int sub = 0; sub < 2; ++sub)
            #pragma unroll
            for (int mt = 0; mt < 4; ++mt)
                #pragma unroll
                for (int j = 0; j < 4; ++j)
                    T[mt * 16 + krow * 4 + j][wave * 32 + sub * 16 + col] = acc[t][sub][mt][j];
        __syncthreads();

        float* obase = orow + (wtA + t) * 128;
        #pragma unroll
        for (int rd = 0; rd < 8; ++rd) {
            const int d = rd * 8 + drow;
            const f32x4 v = *reinterpret_cast<const f32x4*>(&T[d][wl]);
            *reinterpret_cast<f32x4*>(obase + (size_t)d * NWORLD + wl) = v;
        }
    }
}

// ---- kernel 3: zero the stash rows (512..520) ----
__global__ __launch_bounds__(256)
void tail_zero(char* outb)
{
    f32x4* o = reinterpret_cast<f32x4*>(outb + STASH_BYTE);
    const f32x4 z = {0.f, 0.f, 0.f, 0.f};
    const int total = STASH_ROWS * DDIM * NWORLD / 4;   // 294912
    for (int i = blockIdx.x * 256 + threadIdx.x; i < total; i += 288 * 256)
        o[i] = z;
}

extern "C" void kernel_launch(void* const* d_in, const int* in_sizes, int n_in,
                              void* d_out, int out_size, void* d_ws, size_t ws_size,
                              hipStream_t stream) {
    const float* worlds  = (const float*)d_in[0];
    const float* W       = (const float*)d_in[1];
    const int*   nullary = (const int*)d_in[2];
    char*        outb    = (char*)d_out;

    int* counters = (int*)d_ws;          // [0]=zcnt [1]=mcnt
    int* zlist    = counters + 4;

    hipMemsetAsync(counters, 0, 16, stream);
    prep<<<CONV_BLOCKS + NB / 4, 256, 0, stream>>>(W, worlds, nullary, outb, counters, zlist);
    main2<<<GRID_MAIN, 256, 0, stream>>>(outb, counters, zlist);
    tail_zero<<<288, 256, 0, stream>>>(outb);
}